// Round 1
// baseline (629.288 us; speedup 1.0000x reference)
//
#include <hip/hip_runtime.h>
#include <hip/hip_bf16.h>

#define NEG_VAL -1000000000.0f

// Kernel 1: per-node partial dot products.
// a[n] = dot(h[n], W[0:128])   (used when n is a dest)
// c[n] = dot(h[n], W[128:256]) (used when n is a source)
// One 64-lane wave per node; each lane handles 2 of the 128 features via float2.
__global__ void node_dots(const float* __restrict__ h,
                          const float* __restrict__ W,
                          float* __restrict__ a,
                          float* __restrict__ c,
                          int N) {
    int gid  = blockIdx.x * blockDim.x + threadIdx.x;
    int node = gid >> 6;
    int lane = threadIdx.x & 63;
    if (node >= N) return;

    const float2* h2 = (const float2*)(h + (size_t)node * 128);
    float2 v  = h2[lane];
    float2 wd = ((const float2*)W)[lane];           // W[2*lane], W[2*lane+1]
    float2 ws = ((const float2*)(W + 128))[lane];   // W[128+2*lane], ...

    float sd = v.x * wd.x + v.y * wd.y;
    float ss = v.x * ws.x + v.y * ws.y;

    #pragma unroll
    for (int off = 32; off; off >>= 1) {
        sd += __shfl_xor(sd, off, 64);
        ss += __shfl_xor(ss, off, 64);
    }
    if (lane == 0) {
        a[node] = sd;
        c[node] = ss;
    }
}

// Kernel 2: fill the N x N score matrix with NEG. float4 stores, one per thread.
__global__ void fill_neg(float4* __restrict__ out, long long n4) {
    long long i = (long long)blockIdx.x * blockDim.x + threadIdx.x;
    if (i < n4) {
        out[i] = make_float4(NEG_VAL, NEG_VAL, NEG_VAL, NEG_VAL);
    }
}

// Kernel 3: per-edge scatter of the linear-layer output.
__global__ void edge_scatter(const int* __restrict__ src,
                             const int* __restrict__ dst,
                             const float* __restrict__ wgt,
                             const float* __restrict__ a,
                             const float* __restrict__ c,
                             const float* __restrict__ W,
                             const float* __restrict__ b,
                             float* __restrict__ out,
                             int E, int N) {
    int e = blockIdx.x * blockDim.x + threadIdx.x;
    if (e >= E) return;
    int s = src[e];
    int d = dst[e];
    float val = a[d] + c[s] + wgt[e] * W[256] + b[0];
    out[(size_t)d * N + s] = val;
}

extern "C" void kernel_launch(void* const* d_in, const int* in_sizes, int n_in,
                              void* d_out, int out_size, void* d_ws, size_t ws_size,
                              hipStream_t stream) {
    const float* h       = (const float*)d_in[0];  // [N, 128]
    const int*   sources = (const int*)d_in[1];    // [E]
    const int*   dests   = (const int*)d_in[2];    // [E]
    const float* weights = (const float*)d_in[3];  // [E]
    const float* W       = (const float*)d_in[4];  // [257]
    const float* b       = (const float*)d_in[5];  // [1]
    float* out = (float*)d_out;                    // [N, N]

    const int N = in_sizes[0] / 128;               // 12288
    const int E = in_sizes[1];                     // 393216

    float* a = (float*)d_ws;                       // [N]
    float* c = a + N;                              // [N]

    // 1) per-node dots: one wave per node, 4 waves per 256-thread block
    {
        int waves_per_block = 256 / 64;
        int blocks = (N + waves_per_block - 1) / waves_per_block;
        node_dots<<<blocks, 256, 0, stream>>>(h, W, a, c, N);
    }

    // 2) fill with NEG (float4)
    {
        long long n4 = (long long)out_size / 4;    // out_size divisible by 4
        long long blocks = (n4 + 255) / 256;
        fill_neg<<<(int)blocks, 256, 0, stream>>>((float4*)out, n4);
    }

    // 3) scatter edge values
    {
        int blocks = (E + 255) / 256;
        edge_scatter<<<blocks, 256, 0, stream>>>(sources, dests, weights, a, c, W, b,
                                                 out, E, N);
    }
}